// Round 20
// baseline (361.537 us; speedup 1.0000x reference)
//
#include <hip/hip_runtime.h>

#define NN 20000
#define NE 320000
#define EP (NE + NN)          // 340000 edges incl. self loops
#define NG 8
#define HC 256
#define NODE_IN 18
#define HID 64
#define NEG_SLOPE 0.2f
#define BN_EPS 1e-5f

// ---------------- workspace layout (float offsets) ----------------
// audited non-overlapping (bf16 [NN*64] = 640000 FLOATS, not 320000!)
#define OFF_XL    0u                      // bf16 [NN*256] (2.56M fl); also rank[NE] during CSR build
#define OFF_XR    5120000u                // fp32 [NN*256] -> 10240000
#define OFF_H1    10240000u               // bf16 [NN*256] (2.56M fl) -> 12800000
#define OFF_WTL   12800000u               // bf16 [256*256] -> 12832768
#define OFF_WTR   12832768u               // bf16 [256*256] -> 12865536
#define OFF_P     13000000u               // bf16 [NN*64] (640000 fl) -> 13640000
#define OFF_H2B   13700000u               // bf16 [NN*64] (640000 fl) -> 14340000
#define OFF_PERM  14400000u               // int [NN] -> 14420000
#define OFF_ORD   14450000u               // int [NN] -> 14470000
#define OFF_BCNT  14500000u               // int [256]
#define OFF_BB    14510000u               // int [256]
#define OFF_H0    15360000u               // fp32 [NN*64] -> 16640000
#define OFF_H3    16640000u               // fp32 [NN*64] -> 17920000
#define OFF_ZERO  18000000u               // start of zeroed region
#define OFF_CNT   18000000u               // uint cnt [NN]
#define OFF_PSUM  18020000u               // [8*64]
#define OFF_PMAX  18020512u               // [8*64]
#define OFF_PCNT  18021024u               // [16]
#define ZERO_FLOATS (18021040u - 18000000u)
#define OFF_EACSR 18021040u               // [EP*4] CSR-ordered edge attrs
#define OFF_RP    19381040u               // int [NN+1]
#define OFF_SRC   19421041u               // int [EP] (self-loop = LAST slot of row, sign bit)
#define OFF_BSUM  19761056u               // int [32]

#define SCAN_ELEM 1024
#define SCAN_NB ((NN + SCAN_ELEM - 1) / SCAN_ELEM)   // 20
#define NB32 (NN / 32)                                // 625

// k_pre grid partition
#define PRE_CNT_NB 1250
#define PRE_CAST_NB 512
#define PRE_ENC_NB 1250
// k_post grid partition
#define POST_EH_NB (NE / 256)             // 1250 (thread per edge)
#define POST_POOL_NB ((NN + 255) / 256)   // 79

typedef __attribute__((ext_vector_type(8))) short bf16x8_t;
typedef __attribute__((ext_vector_type(4))) float f32x4_t;

__device__ __forceinline__ ushort f2bf(float f) {   // RNE float->bf16
  unsigned u = __float_as_uint(f);
  unsigned r = (u + 0x7fffu + ((u >> 16) & 1u)) >> 16;
  return (ushort)r;
}
__device__ __forceinline__ float bf2f(ushort b) {
  return __uint_as_float(((unsigned)b) << 16);
}

// ------------------------------------------------------------------
// K_pre: count (atomic rank) || g2 weight casts || encoder — independent.
#define ENC_NPW 4
__global__ __launch_bounds__(256) void k_pre(
    const int* __restrict__ ei, unsigned* __restrict__ cnt, int* __restrict__ rank,
    const float* __restrict__ Wl, const float* __restrict__ Wr,
    ushort* __restrict__ WtL, ushort* __restrict__ WtR,
    const float* __restrict__ x, const float* __restrict__ ew1, const float* __restrict__ eb1,
    const float* __restrict__ ew2, const float* __restrict__ eb2, float* __restrict__ h0) {
  __shared__ float W1[NODE_IN * HID];
  __shared__ float W2[HID * HID];
  __shared__ float B1s[HID];
  __shared__ float B2s[HID];
  __shared__ float hid_s[4][HID];
  const int b = blockIdx.x;
  const int tid = threadIdx.x;
  if (b < PRE_CNT_NB) {
    int e = b * 256 + tid;
    if (e < NE) {
      int d = ei[NE + e];
      rank[e] = (int)atomicAdd(&cnt[d], 1u);
    }
    return;
  }
  if (b < PRE_CNT_NB + PRE_CAST_NB) {
    int bb = b - PRE_CNT_NB;
    const float* W = (bb < 256) ? Wl : Wr;
    ushort* Wt = (bb < 256) ? WtL : WtR;
    int k = bb & 255;
    Wt[tid * 256 + k] = f2bf(W[k * 256 + tid]);
    return;
  }
  // encoder
  const int eb = b - PRE_CNT_NB - PRE_CAST_NB;
  for (int i = tid; i < NODE_IN * HID; i += 256) W1[i] = ew1[i];
  for (int i = tid; i < HID * HID; i += 256) W2[i] = ew2[i];
  if (tid < HID) { B1s[tid] = eb1[tid]; B2s[tid] = eb2[tid]; }
  __syncthreads();
  const int lane = tid & 63;
  const int w = tid >> 6;
  #pragma unroll
  for (int t = 0; t < ENC_NPW; t++) {
    const int n = eb * (4 * ENC_NPW) + w * ENC_NPW + t;
    const float* xp = &x[(size_t)n * NODE_IN];
    float s = B1s[lane];
    #pragma unroll
    for (int i = 0; i < NODE_IN; i++) s += xp[i] * W1[i * HID + lane];
    hid_s[w][lane] = fmaxf(s, 0.f);
    float o = B2s[lane];
    #pragma unroll 8
    for (int k = 0; k < HID; k++) o += hid_s[w][k] * W2[k * HID + lane];
    h0[(size_t)n * HID + lane] = o;
  }
}

// ------------------------------------------------------------------
__global__ __launch_bounds__(256) void k_scan_blk(
    const unsigned* __restrict__ cnt, int* __restrict__ row_ptr, int* __restrict__ bsums) {
  __shared__ int wsum[4];
  const int tid = threadIdx.x, lane = tid & 63, w = tid >> 6;
  const int i0 = blockIdx.x * SCAN_ELEM + tid * 4;
  int v0 = (i0 + 0 < NN) ? ((int)cnt[i0 + 0] + 1) : 0;
  int v1 = (i0 + 1 < NN) ? ((int)cnt[i0 + 1] + 1) : 0;
  int v2 = (i0 + 2 < NN) ? ((int)cnt[i0 + 2] + 1) : 0;
  int v3 = (i0 + 3 < NN) ? ((int)cnt[i0 + 3] + 1) : 0;
  int tsum = v0 + v1 + v2 + v3;
  int incl = tsum;
  #pragma unroll
  for (int off = 1; off < 64; off <<= 1) {
    int t = __shfl_up(incl, off);
    if (lane >= off) incl += t;
  }
  if (lane == 63) wsum[w] = incl;
  __syncthreads();
  int p = incl - tsum;
  #pragma unroll
  for (int k = 0; k < 4; k++) if (k < w) p += wsum[k];
  if (i0 + 0 < NN) row_ptr[i0 + 0] = p;
  if (i0 + 1 < NN) row_ptr[i0 + 1] = p + v0;
  if (i0 + 2 < NN) row_ptr[i0 + 2] = p + v0 + v1;
  if (i0 + 3 < NN) row_ptr[i0 + 3] = p + v0 + v1 + v2;
  if (tid == 0) bsums[blockIdx.x] = wsum[0] + wsum[1] + wsum[2] + wsum[3];
}

__global__ __launch_bounds__(256) void k_scan_add(
    const int* __restrict__ bsums, int* __restrict__ row_ptr) {
  const int b = blockIdx.x, tid = threadIdx.x;
  int off = 0;
  for (int j = 0; j < b; j++) off += bsums[j];
  const int i0 = b * SCAN_ELEM + tid * 4;
  #pragma unroll
  for (int k = 0; k < 4; k++) {
    int i = i0 + k;
    if (i < NN) row_ptr[i] += off;
  }
  if (b == 0 && tid == 0) row_ptr[NN] = EP;
}

// ------------------------------------------------------------------
// Degree-bucket sort: histogram+rank, scan, scatter -> perm.
__global__ __launch_bounds__(256) void k_bucket(
    const unsigned* __restrict__ cnt, int* __restrict__ bcnt, int* __restrict__ ord) {
  int i = blockIdx.x * 256 + threadIdx.x;
  if (i >= NN) return;
  int d = (int)cnt[i];
  if (d > 255) d = 255;
  ord[i] = atomicAdd(&bcnt[d], 1);
}

__global__ void k_bscan(const int* __restrict__ bcnt, int* __restrict__ bb) {
  __shared__ int lds[256];
  int tid = threadIdx.x;
  lds[tid] = bcnt[tid];
  __syncthreads();
  for (int off = 1; off < 256; off <<= 1) {
    int t = (tid >= off) ? lds[tid - off] : 0;
    __syncthreads();
    lds[tid] += t;
    __syncthreads();
  }
  bb[tid] = lds[tid] - bcnt[tid];   // exclusive
}

__global__ __launch_bounds__(256) void k_perm(
    const unsigned* __restrict__ cnt, const int* __restrict__ ord,
    const int* __restrict__ bb, int* __restrict__ perm) {
  int i = blockIdx.x * 256 + threadIdx.x;
  if (i >= NN) return;
  int d = (int)cnt[i];
  if (d > 255) d = 255;
  perm[bb[d] + ord[i]] = i;
}

// ------------------------------------------------------------------
__global__ __launch_bounds__(256) void k_csr_scatter(
    const int* __restrict__ ei, const int* __restrict__ rank,
    const int* __restrict__ row_ptr, const float* __restrict__ ea,
    int* __restrict__ srcs, float* __restrict__ ea_csr) {
  int e = blockIdx.x * 256 + threadIdx.x;
  if (e >= NE) return;
  int s = ei[e], d = ei[NE + e];
  int p = row_ptr[d] + rank[e];
  srcs[p] = s;
  *(float4*)&ea_csr[(size_t)p * 4] = *(const float4*)&ea[(size_t)e * 4];
}

// K_loop_row: wave-per-node self-loop mean.
__global__ __launch_bounds__(256) void k_loop_row(
    const int* __restrict__ row_ptr, int* __restrict__ srcs, float* __restrict__ ea_csr) {
  int lane = threadIdx.x & 63, w = threadIdx.x >> 6;
  int i = blockIdx.x * 4 + w;
  int start = row_ptr[i], last = row_ptr[i + 1] - 1;
  float s = 0.f;
  int base = start * 4;
  int nfl = (last - start) * 4;
  for (int f = lane; f < nfl; f += 64) s += ea_csr[base + f];
  s += __shfl_xor(s, 4);
  s += __shfl_xor(s, 8);
  s += __shfl_xor(s, 16);
  s += __shfl_xor(s, 32);
  float c = (float)(last - start);
  if (c < 1.f) c = 1.f;
  if (lane < 4) ea_csr[(size_t)last * 4 + lane] = s / c;
  if (lane == 0) srcs[last] = i | (int)0x80000000;
}

// ------------------------------------------------------------------
// K4: fp32 vector GEMM (layer-1, K=64), DUAL.
__global__ __launch_bounds__(256) void k_gemm256_dual(
    const float* __restrict__ A, const float* __restrict__ Wl_, const float* __restrict__ Wr_,
    ushort* __restrict__ OUTbf, float* __restrict__ OUTf) {
  const bool first = blockIdx.x < NB32;
  const float* __restrict__ W = first ? Wl_ : Wr_;
  const int n0 = (first ? blockIdx.x : blockIdx.x - NB32) * 32;
  __shared__ float Wlds[32 * 256];
  __shared__ float Al[32 * 36];
  const int tid = threadIdx.x;
  const int tx = tid & 63, ty = tid >> 6;
  float acc[8][4];
  #pragma unroll
  for (int m = 0; m < 8; m++)
    #pragma unroll
    for (int c = 0; c < 4; c++) acc[m][c] = 0.f;

  for (int kt = 0; kt < 64; kt += 32) {
    #pragma unroll
    for (int r = 0; r < 8; r++) {
      int i4 = tid + 256 * r;
      int row = i4 >> 6;
      int col4 = (i4 & 63) * 4;
      *(float4*)&Wlds[row * 256 + col4] = *(const float4*)&W[(size_t)(kt + row) * 256 + col4];
    }
    {
      int m = tid >> 3, kk = (tid & 7) * 4;
      float4 av = *(const float4*)&A[(size_t)(n0 + m) * 64 + kt + kk];
      Al[(kk + 0) * 36 + m] = av.x;
      Al[(kk + 1) * 36 + m] = av.y;
      Al[(kk + 2) * 36 + m] = av.z;
      Al[(kk + 3) * 36 + m] = av.w;
    }
    __syncthreads();
    #pragma unroll 8
    for (int k = 0; k < 32; k++) {
      float4 b = *(float4*)&Wlds[k * 256 + tx * 4];
      float4 a0v = *(float4*)&Al[k * 36 + ty * 8];
      float4 a1v = *(float4*)&Al[k * 36 + ty * 8 + 4];
      float am[8] = {a0v.x, a0v.y, a0v.z, a0v.w, a1v.x, a1v.y, a1v.z, a1v.w};
      #pragma unroll
      for (int m = 0; m < 8; m++) {
        acc[m][0] += am[m] * b.x;
        acc[m][1] += am[m] * b.y;
        acc[m][2] += am[m] * b.z;
        acc[m][3] += am[m] * b.w;
      }
    }
    __syncthreads();
  }
  if (first) {
    #pragma unroll
    for (int m = 0; m < 8; m++) {
      ushort4 o = {f2bf(acc[m][0]), f2bf(acc[m][1]), f2bf(acc[m][2]), f2bf(acc[m][3])};
      *(ushort4*)&OUTbf[(size_t)(n0 + ty * 8 + m) * 256 + tx * 4] = o;
    }
  } else {
    #pragma unroll
    for (int m = 0; m < 8; m++) {
      float4 o = {acc[m][0], acc[m][1], acc[m][2], acc[m][3]};
      *(float4*)&OUTf[(size_t)(n0 + ty * 8 + m) * 256 + tx * 4] = o;
    }
  }
}

// ------------------------------------------------------------------
// K4b: MFMA bf16 GEMM (layer-2, K=256), DUAL.
__global__ __launch_bounds__(256) void k_gemm_mfma_dual(
    const ushort* __restrict__ A, const ushort* __restrict__ wtl,
    const ushort* __restrict__ wtr, ushort* __restrict__ OUTbf, float* __restrict__ OUTf) {
  const bool first = blockIdx.x < NB32;
  const ushort* __restrict__ Wt = first ? wtl : wtr;
  const int n0 = (first ? blockIdx.x : blockIdx.x - NB32) * 32;
  __shared__ ushort Asub[32][72];
  __shared__ ushort Wsub[256][72];
  const int tid = threadIdx.x;
  const int lane = tid & 63;
  const int w = tid >> 6;
  const int lr = lane & 15;
  const int lk = (lane >> 4) * 8;

  f32x4_t acc[2][4];
  #pragma unroll
  for (int m = 0; m < 2; m++)
    #pragma unroll
    for (int n = 0; n < 4; n++) acc[m][n] = (f32x4_t){0.f, 0.f, 0.f, 0.f};

  for (int kt = 0; kt < 256; kt += 64) {
    {
      int r = tid >> 3, seg = (tid & 7) * 8;
      *(uint4*)&Asub[r][seg] = *(const uint4*)&A[(size_t)(n0 + r) * 256 + kt + seg];
    }
    #pragma unroll
    for (int rep = 0; rep < 8; rep++) {
      int idx = rep * 256 + tid;
      int r = idx >> 3, seg = (idx & 7) * 8;
      *(uint4*)&Wsub[r][seg] = *(const uint4*)&Wt[(size_t)r * 256 + kt + seg];
    }
    __syncthreads();
    #pragma unroll
    for (int kk = 0; kk < 2; kk++) {
      bf16x8_t af0 = *(bf16x8_t*)&Asub[lr][kk * 32 + lk];
      bf16x8_t af1 = *(bf16x8_t*)&Asub[16 + lr][kk * 32 + lk];
      #pragma unroll
      for (int n = 0; n < 4; n++) {
        bf16x8_t bfr = *(bf16x8_t*)&Wsub[w * 64 + n * 16 + lr][kk * 32 + lk];
        acc[0][n] = __builtin_amdgcn_mfma_f32_16x16x32_bf16(af0, bfr, acc[0][n], 0, 0, 0);
        acc[1][n] = __builtin_amdgcn_mfma_f32_16x16x32_bf16(af1, bfr, acc[1][n], 0, 0, 0);
      }
    }
    __syncthreads();
  }
  const int crow = (lane >> 4) * 4;
  #pragma unroll
  for (int m = 0; m < 2; m++) {
    #pragma unroll
    for (int n = 0; n < 4; n++) {
      int col = w * 64 + n * 16 + lr;
      #pragma unroll
      for (int r = 0; r < 4; r++) {
        int row = n0 + m * 16 + crow + r;
        if (first) OUTbf[(size_t)row * 256 + col] = f2bf(acc[m][n][r]);
        else       OUTf[(size_t)row * 256 + col] = acc[m][n][r];
      }
    }
  }
}

// ------------------------------------------------------------------
// K5: fused GATv2 — 4-edge unroll, quad streams, direct-exp, degree-sorted.
#define GAT_EDGE(A_, U_, DN_, C0_, C1_, C2_, C3_)                                  \
  {                                                                                \
    float xx_ = bf2f((U_).x), xy_ = bf2f((U_).y), xz_ = bf2f((U_).z), xw_ = bf2f((U_).w); \
    float m0_ = xx_ + xrd.x + (A_).x * we0.x + (A_).y * we1.x + (A_).z * we2.x + (A_).w * we3.x; \
    float m1_ = xy_ + xrd.y + (A_).x * we0.y + (A_).y * we1.y + (A_).z * we2.y + (A_).w * we3.y; \
    float m2_ = xz_ + xrd.z + (A_).x * we0.z + (A_).y * we1.z + (A_).z * we2.z + (A_).w * we3.z; \
    float m3_ = xw_ + xrd.w + (A_).x * we0.w + (A_).y * we1.w + (A_).z * we2.w + (A_).w * we3.w; \
    m0_ = fmaxf(m0_, NEG_SLOPE * m0_);                                             \
    m1_ = fmaxf(m1_, NEG_SLOPE * m1_);                                             \
    m2_ = fmaxf(m2_, NEG_SLOPE * m2_);                                             \
    m3_ = fmaxf(m3_, NEG_SLOPE * m3_);                                             \
    float lg_ = m0_ * attv.x + m1_ * attv.y + m2_ * attv.z + m3_ * attv.w;         \
    lg_ += __shfl_xor(lg_, 1);                                                     \
    lg_ += __shfl_xor(lg_, 2);                                                     \
    lg_ += __shfl_xor(lg_, 4);                                                     \
    lg_ += __shfl_xor(lg_, 8);                                                     \
    float p_ = __expf(lg_);                                                        \
    DN_ += p_;                                                                     \
    C0_ = fmaf(p_, xx_, C0_);                                                      \
    C1_ = fmaf(p_, xy_, C1_);                                                      \
    C2_ = fmaf(p_, xz_, C2_);                                                      \
    C3_ = fmaf(p_, xw_, C3_);                                                      \
  }

template <int CONCAT>
__global__ __launch_bounds__(256) void k_gat_fused(
    const ushort* __restrict__ xl, const float* __restrict__ xr,
    const float* __restrict__ we, const float* __restrict__ att,
    const int* __restrict__ srcs, const float* __restrict__ ea_csr,
    const int* __restrict__ row_ptr, const int* __restrict__ perm,
    const float* __restrict__ bias, const float* __restrict__ bng,
    const float* __restrict__ bnb, void* __restrict__ outp,
    ushort* __restrict__ outbf2) {
  const int lane = threadIdx.x & 63;
  const int w = threadIdx.x >> 6;
  const int i = perm[blockIdx.x * 4 + w];
  const int c0 = lane * 4;

  const float4 attv = *(const float4*)&att[c0];
  const float4 we0 = *(const float4*)&we[0 * HC + c0];
  const float4 we1 = *(const float4*)&we[1 * HC + c0];
  const float4 we2 = *(const float4*)&we[2 * HC + c0];
  const float4 we3 = *(const float4*)&we[3 * HC + c0];
  const float4 xrd = *(const float4*)&xr[(size_t)i * HC + c0];

  const int start = row_ptr[i];
  const int deg = row_ptr[i + 1] - start;

  float dnA = 0.f, aA0 = 0.f, aA1 = 0.f, aA2 = 0.f, aA3 = 0.f;
  float dnB = 0.f, aB0 = 0.f, aB1 = 0.f, aB2 = 0.f, aB3 = 0.f;
  float dnC = 0.f, aC0 = 0.f, aC1 = 0.f, aC2 = 0.f, aC3 = 0.f;
  float dnD = 0.f, aD0 = 0.f, aD1 = 0.f, aD2 = 0.f, aD3 = 0.f;

  for (int base = 0; base < deg; base += 64) {
    int rem = deg - base;
    if (rem > 64) rem = 64;
    int sv = 0;
    if (lane < rem) sv = srcs[start + base + lane] & 0x7fffffff;
    const float4* eaB = (const float4*)&ea_csr[(size_t)(start + base) * 4];
    int jj = 0;
    for (; jj + 4 <= rem; jj += 4) {
      int s0 = __shfl(sv, jj);
      int s1 = __shfl(sv, jj + 1);
      int s2 = __shfl(sv, jj + 2);
      int s3 = __shfl(sv, jj + 3);
      float4 a0 = eaB[jj];
      float4 a1 = eaB[jj + 1];
      float4 a2 = eaB[jj + 2];
      float4 a3 = eaB[jj + 3];
      ushort4 u0 = *(const ushort4*)&xl[(size_t)s0 * HC + c0];
      ushort4 u1 = *(const ushort4*)&xl[(size_t)s1 * HC + c0];
      ushort4 u2 = *(const ushort4*)&xl[(size_t)s2 * HC + c0];
      ushort4 u3 = *(const ushort4*)&xl[(size_t)s3 * HC + c0];
      GAT_EDGE(a0, u0, dnA, aA0, aA1, aA2, aA3);
      GAT_EDGE(a1, u1, dnB, aB0, aB1, aB2, aB3);
      GAT_EDGE(a2, u2, dnC, aC0, aC1, aC2, aC3);
      GAT_EDGE(a3, u3, dnD, aD0, aD1, aD2, aD3);
    }
    for (; jj < rem; ++jj) {   // tail edges -> stream A
      int s0 = __shfl(sv, jj);
      float4 a0 = eaB[jj];
      ushort4 u0 = *(const ushort4*)&xl[(size_t)s0 * HC + c0];
      GAT_EDGE(a0, u0, dnA, aA0, aA1, aA2, aA3);
    }
  }

  float rinv = 1.f / ((dnA + dnB) + (dnC + dnD));
  float acc0 = ((aA0 + aB0) + (aC0 + aD0)) * rinv;
  float acc1 = ((aA1 + aB1) + (aC1 + aD1)) * rinv;
  float acc2 = ((aA2 + aB2) + (aC2 + aD2)) * rinv;
  float acc3 = ((aA3 + aB3) + (aC3 + aD3)) * rinv;

  const float inv_sqrt = rsqrtf(1.f + BN_EPS);
  if (CONCAT) {
    float4 bi = *(const float4*)&bias[c0];
    float4 g = *(const float4*)&bng[c0];
    float4 bb = *(const float4*)&bnb[c0];
    float v0 = (acc0 + bi.x) * (g.x * inv_sqrt) + bb.x;
    float v1 = (acc1 + bi.y) * (g.y * inv_sqrt) + bb.y;
    float v2 = (acc2 + bi.z) * (g.z * inv_sqrt) + bb.z;
    float v3 = (acc3 + bi.w) * (g.w * inv_sqrt) + bb.w;
    v0 = (v0 > 0.f) ? v0 : (__expf(v0) - 1.f);
    v1 = (v1 > 0.f) ? v1 : (__expf(v1) - 1.f);
    v2 = (v2 > 0.f) ? v2 : (__expf(v2) - 1.f);
    v3 = (v3 > 0.f) ? v3 : (__expf(v3) - 1.f);
    ushort* op = (ushort*)outp;                      // h1 stored bf16 for MFMA
    ushort4 o = {f2bf(v0), f2bf(v1), f2bf(v2), f2bf(v3)};
    *(ushort4*)&op[(size_t)i * HC + c0] = o;
  } else {
    acc0 += __shfl_xor(acc0, 16); acc0 += __shfl_xor(acc0, 32);
    acc1 += __shfl_xor(acc1, 16); acc1 += __shfl_xor(acc1, 32);
    acc2 += __shfl_xor(acc2, 16); acc2 += __shfl_xor(acc2, 32);
    acc3 += __shfl_xor(acc3, 16); acc3 += __shfl_xor(acc3, 32);
    if (lane < 16) {
      int cc = lane * 4;
      float4 bi = *(const float4*)&bias[cc];
      float4 g = *(const float4*)&bng[cc];
      float4 bb = *(const float4*)&bnb[cc];
      float v0 = (0.25f * acc0 + bi.x) * (g.x * inv_sqrt) + bb.x;
      float v1 = (0.25f * acc1 + bi.y) * (g.y * inv_sqrt) + bb.y;
      float v2 = (0.25f * acc2 + bi.z) * (g.z * inv_sqrt) + bb.z;
      float v3 = (0.25f * acc3 + bi.w) * (g.w * inv_sqrt) + bb.w;
      v0 = (v0 > 0.f) ? v0 : (__expf(v0) - 1.f);
      v1 = (v1 > 0.f) ? v1 : (__expf(v1) - 1.f);
      v2 = (v2 > 0.f) ? v2 : (__expf(v2) - 1.f);
      v3 = (v3 > 0.f) ? v3 : (__expf(v3) - 1.f);
      float* op = (float*)outp;
      float4 o = {v0, v1, v2, v3};
      *(float4*)&op[(size_t)i * 64 + cc] = o;
      ushort4 ob = {f2bf(v0), f2bf(v1), f2bf(v2), f2bf(v3)};
      *(ushort4*)&outbf2[(size_t)i * 64 + cc] = ob;  // h2 bf16 mirror for SAGE
    }
  }
}

// ------------------------------------------------------------------
// K8: fused SAGE (bf16 gathers, degree-sorted) + edge-head projections.
__global__ __launch_bounds__(256) void k_sage(
    const float* __restrict__ h2, const ushort* __restrict__ h2b,
    const int* __restrict__ row_ptr, const int* __restrict__ perm,
    const int* __restrict__ srcs, const unsigned* __restrict__ cnt,
    const float* __restrict__ wl, const float* __restrict__ bl,
    const float* __restrict__ wr, const float* __restrict__ bng,
    const float* __restrict__ bnb, const float* __restrict__ w1eh,
    float* __restrict__ h3, ushort* __restrict__ P) {
  __shared__ float Wc[64][64];      // 16 KB: [k][j] = W1a/W1b column mix
  __shared__ float agg_s[4][64];
  __shared__ float h2_s[4][64];
  int tid = threadIdx.x;
  for (int idx = tid; idx < 4096; idx += 256) {
    int k = idx >> 6, j = idx & 63;
    Wc[k][j] = (j < 32) ? w1eh[k * 32 + j] : w1eh[(64 + k) * 32 + (j - 32)];
  }
  int lane = tid & 63;
  int w = tid >> 6;
  int i = perm[blockIdx.x * 4 + w];
  int start = row_ptr[i];
  int nreal = row_ptr[i + 1] - 1 - start;
  float a0 = 0.f, a1 = 0.f, a2 = 0.f, a3 = 0.f;
  for (int base = 0; base < nreal; base += 64) {
    int rem = nreal - base;
    if (rem > 64) rem = 64;
    int sv = 0;
    if (lane < rem) sv = srcs[start + base + lane];
    int jj = 0;
    for (; jj + 4 <= rem; jj += 4) {
      int s0 = __shfl(sv, jj);
      int s1 = __shfl(sv, jj + 1);
      int s2 = __shfl(sv, jj + 2);
      int s3 = __shfl(sv, jj + 3);
      a0 += bf2f(h2b[(size_t)s0 * 64 + lane]);
      a1 += bf2f(h2b[(size_t)s1 * 64 + lane]);
      a2 += bf2f(h2b[(size_t)s2 * 64 + lane]);
      a3 += bf2f(h2b[(size_t)s3 * 64 + lane]);
    }
    for (; jj < rem; ++jj) {
      int s0 = __shfl(sv, jj);
      a0 += bf2f(h2b[(size_t)s0 * 64 + lane]);
    }
  }
  float a = (a0 + a1) + (a2 + a3);
  float c = (float)cnt[i];
  if (c < 1.f) c = 1.f;
  agg_s[w][lane] = a / c;
  h2_s[w][lane] = h2[(size_t)i * 64 + lane];
  __syncthreads();                  // covers Wc staging + agg/h2 writes
  float s = bl[lane];
  #pragma unroll 4
  for (int k = 0; k < 64; k++)
    s += agg_s[w][k] * wl[k * 64 + lane] + h2_s[w][k] * wr[k * 64 + lane];
  s = s * (bng[lane] * rsqrtf(1.f + BN_EPS)) + bnb[lane];
  s = fmaxf(s, 0.f);
  h3[(size_t)i * 64 + lane] = s;
  agg_s[w][lane] = s;               // wave-local reuse: h3 row broadcast
  float p = 0.f;
  #pragma unroll 4
  for (int k = 0; k < 64; k++) p += agg_s[w][k] * Wc[k][lane];
  P[(size_t)i * 64 + lane] = f2bf(p);
}

// ------------------------------------------------------------------
// K_post: edge head (thread/edge, gathers bf16 P) || pooling.
__global__ __launch_bounds__(256) void k_post(
    const ushort* __restrict__ P, const int* __restrict__ ei,
    const float* __restrict__ ea, const float* __restrict__ w1eh,
    const float* __restrict__ b1, const float* __restrict__ w2,
    const float* __restrict__ b2, float* __restrict__ out,
    const float* __restrict__ h3, const int* __restrict__ batch,
    float* __restrict__ psum, float* __restrict__ pmax, float* __restrict__ pcnt) {
  const int tid = threadIdx.x;
  if (blockIdx.x >= POST_EH_NB) {
    // ---- pooling branch ----
    int pb = blockIdx.x - POST_EH_NB;
    int j = tid & 63, grp = tid >> 6;
    int nbase = pb * 256 + grp * 64;
    float s = 0.f, m = 0.f, cn = 0.f;
    int cur = -1;
    for (int t = 0; t < 64; t++) {
      int n = nbase + t;
      if (n >= NN) break;
      int g = batch[n];
      if (g != cur) {
        if (cur >= 0) {
          atomicAdd(&psum[cur * 64 + j], s);
          atomicMax((int*)&pmax[cur * 64 + j], __float_as_int(m));
          if (j == 0) atomicAdd(&pcnt[cur], cn);
        }
        cur = g; s = 0.f; m = 0.f; cn = 0.f;
      }
      float v = h3[(size_t)n * 64 + j];
      s += v; m = fmaxf(m, v); cn += 1.f;
    }
    if (cur >= 0) {
      atomicAdd(&psum[cur * 64 + j], s);
      atomicMax((int*)&pmax[cur * 64 + j], __float_as_int(m));
      if (j == 0) atomicAdd(&pcnt[cur], cn);
    }
    return;
  }
  // ---- edge head branch: one thread per edge ----
  const int e = blockIdx.x * 256 + tid;
  const int sn = ei[e], dn = ei[NE + e];
  const ushort* Ps = &P[(size_t)sn * 64];        // src projection (cols 0..31)
  const ushort* Pd = &P[(size_t)dn * 64 + 32];   // dst projection (cols 32..63)
  float acc[32];
  #pragma unroll
  for (int f = 0; f < 4; f++) {
    ushort u1[8], u2[8];
    *(uint4*)u1 = *(const uint4*)&Ps[f * 8];
    *(uint4*)u2 = *(const uint4*)&Pd[f * 8];
    #pragma unroll
    for (int j = 0; j < 8; j++) acc[f * 8 + j] = bf2f(u1[j]) + bf2f(u2[j]);
  }
  float4 av = *(const float4*)&ea[(size_t)e * 4];
  const float* w1c = &w1eh[128 * 32];           // rows 128..131 (edge_attr part)
  float z = 0.f;
  #pragma unroll
  for (int j = 0; j < 32; j++) {
    float v = acc[j] + b1[j]
            + av.x * w1c[j] + av.y * w1c[32 + j]
            + av.z * w1c[64 + j] + av.w * w1c[96 + j];
    z += fmaxf(v, 0.f) * w2[j];
  }
  out[e] = 1.f / (1.f + __expf(-(z + b2[0])));
}

// ------------------------------------------------------------------
__global__ void k_graph_head(
    const float* __restrict__ psum, const float* __restrict__ pmax,
    const float* __restrict__ pcnt,
    const float* __restrict__ w1, const float* __restrict__ b1,
    const float* __restrict__ w2, const float* __restrict__ b2,
    const float* __restrict__ w3, const float* __restrict__ b3,
    float* __restrict__ out) {
  __shared__ float hp[128];
  __shared__ float z1[64];
  __shared__ float z2[32];
  int g = blockIdx.x, j = threadIdx.x;
  float c = pcnt[g];
  if (c < 1.f) c = 1.f;
  hp[j] = psum[g * 64 + j] / c;
  hp[64 + j] = pmax[g * 64 + j];
  __syncthreads();
  float s = b1[j];
  #pragma unroll 8
  for (int k = 0; k < 128; k++) s += hp[k] * w1[k * 64 + j];
  z1[j] = fmaxf(s, 0.f);
  __syncthreads();
  if (j < 32) {
    float s2 = b2[j];
    #pragma unroll 8
    for (int k = 0; k < 64; k++) s2 += z1[k] * w2[k * 32 + j];
    z2[j] = fmaxf(s2, 0.f);
  }
  __syncthreads();
  if (j == 0) {
    float s3 = b3[0];
    #pragma unroll
    for (int k = 0; k < 32; k++) s3 += z2[k] * w3[k];
    out[g] = 1.f / (1.f + expf(-s3));
  }
}

// ------------------------------------------------------------------
extern "C" void kernel_launch(void* const* d_in, const int* in_sizes, int n_in,
                              void* d_out, int out_size, void* d_ws, size_t ws_size,
                              hipStream_t stream) {
  const float* x         = (const float*)d_in[0];
  const float* edge_attr = (const float*)d_in[1];
  const float* enc_w1 = (const float*)d_in[2];
  const float* enc_b1 = (const float*)d_in[3];
  const float* enc_w2 = (const float*)d_in[4];
  const float* enc_b2 = (const float*)d_in[5];
  const float* g1_wl = (const float*)d_in[6];
  const float* g1_wr = (const float*)d_in[7];
  const float* g1_we = (const float*)d_in[8];
  const float* g1_att = (const float*)d_in[9];
  const float* g1_b = (const float*)d_in[10];
  const float* bn1_g = (const float*)d_in[11];
  const float* bn1_b = (const float*)d_in[12];
  const float* g2_wl = (const float*)d_in[13];
  const float* g2_wr = (const float*)d_in[14];
  const float* g2_we = (const float*)d_in[15];
  const float* g2_att = (const float*)d_in[16];
  const float* g2_b = (const float*)d_in[17];
  const float* bn2_g = (const float*)d_in[18];
  const float* bn2_b = (const float*)d_in[19];
  const float* sage_wl = (const float*)d_in[20];
  const float* sage_bl = (const float*)d_in[21];
  const float* sage_wr = (const float*)d_in[22];
  const float* bn3_g = (const float*)d_in[23];
  const float* bn3_b = (const float*)d_in[24];
  const float* gh_w1 = (const float*)d_in[25];
  const float* gh_b1 = (const float*)d_in[26];
  const float* gh_w2 = (const float*)d_in[27];
  const float* gh_b2 = (const float*)d_in[28];
  const float* gh_w3 = (const float*)d_in[29];
  const float* gh_b3 = (const float*)d_in[30];
  const float* eh_w1 = (const float*)d_in[31];
  const float* eh_b1 = (const float*)d_in[32];
  const float* eh_w2 = (const float*)d_in[33];
  const float* eh_b2 = (const float*)d_in[34];
  const int* ei    = (const int*)d_in[35];
  const int* batch = (const int*)d_in[36];
  float* out = (float*)d_out;

  float* ws = (float*)d_ws;
  ushort* xlbf = (ushort*)(ws + OFF_XL);
  float* xr = ws + OFF_XR;
  ushort* h1bf = (ushort*)(ws + OFF_H1);
  ushort* wtl = (ushort*)(ws + OFF_WTL);
  ushort* wtr = (ushort*)(ws + OFF_WTR);
  ushort* Pproj = (ushort*)(ws + OFF_P);
  ushort* h2b = (ushort*)(ws + OFF_H2B);
  int* perm = (int*)(ws + OFF_PERM);
  int* ord = (int*)(ws + OFF_ORD);
  int* bcnt = (int*)(ws + OFF_BCNT);
  int* bb = (int*)(ws + OFF_BB);
  float* h0 = ws + OFF_H0;   // later h2
  float* h3 = ws + OFF_H3;
  unsigned* cnt = (unsigned*)(ws + OFF_CNT);
  float* psum = ws + OFF_PSUM;
  float* pmax = ws + OFF_PMAX;
  float* pcnt = ws + OFF_PCNT;
  float* ea_csr = ws + OFF_EACSR;
  int* row_ptr = (int*)(ws + OFF_RP);
  int* srcs = (int*)(ws + OFF_SRC);
  int* bsums = (int*)(ws + OFF_BSUM);
  int* rank = (int*)(ws + OFF_XL);   // transient

  hipMemsetAsync(ws + OFF_ZERO, 0, ZERO_FLOATS * sizeof(float), stream);
  hipMemsetAsync(ws + OFF_BCNT, 0, 256 * sizeof(int), stream);

  k_pre<<<PRE_CNT_NB + PRE_CAST_NB + PRE_ENC_NB, 256, 0, stream>>>(
      ei, cnt, rank, g2_wl, g2_wr, wtl, wtr,
      x, enc_w1, enc_b1, enc_w2, enc_b2, h0);
  k_scan_blk<<<SCAN_NB, 256, 0, stream>>>(cnt, row_ptr, bsums);
  k_scan_add<<<SCAN_NB, 256, 0, stream>>>(bsums, row_ptr);
  k_bucket<<<(NN + 255) / 256, 256, 0, stream>>>(cnt, bcnt, ord);
  k_bscan<<<1, 256, 0, stream>>>(bcnt, bb);
  k_perm<<<(NN + 255) / 256, 256, 0, stream>>>(cnt, ord, bb, perm);
  k_csr_scatter<<<NE / 256, 256, 0, stream>>>(ei, rank, row_ptr, edge_attr, srcs, ea_csr);
  k_loop_row<<<NN / 4, 256, 0, stream>>>(row_ptr, srcs, ea_csr);

  // ---- GAT layer 1 (fp32 vector GEMMs, K=64, dual launch) ----
  k_gemm256_dual<<<2 * NB32, 256, 0, stream>>>(h0, g1_wl, g1_wr, xlbf, xr);
  k_gat_fused<1><<<NN / 4, 256, 0, stream>>>(xlbf, xr, g1_we, g1_att, srcs, ea_csr,
                                             row_ptr, perm, g1_b, bn1_g, bn1_b, (void*)h1bf, nullptr);

  // ---- GAT layer 2 (MFMA bf16 GEMMs, K=256, dual launch) ----
  k_gemm_mfma_dual<<<2 * NB32, 256, 0, stream>>>(h1bf, wtl, wtr, xlbf, xr);
  k_gat_fused<0><<<NN / 4, 256, 0, stream>>>(xlbf, xr, g2_we, g2_att, srcs, ea_csr,
                                             row_ptr, perm, g2_b, bn2_g, bn2_b, (void*)h0, h2b);

  // ---- SAGE (+ edge-head projections) ----
  k_sage<<<NN / 4, 256, 0, stream>>>(h0, h2b, row_ptr, perm, srcs, cnt, sage_wl, sage_bl, sage_wr,
                                     bn3_g, bn3_b, eh_w1, h3, Pproj);

  // ---- edge head || pooling, then graph head ----
  k_post<<<POST_EH_NB + POST_POOL_NB, 256, 0, stream>>>(
      Pproj, ei, edge_attr, eh_w1, eh_b1, eh_w2, eh_b2, out + NG,
      h3, batch, psum, pmax, pcnt);
  k_graph_head<<<NG, 64, 0, stream>>>(psum, pmax, pcnt, gh_w1, gh_b1, gh_w2, gh_b2, gh_w3, gh_b3, out);
}

// Round 21
// 305.560 us; speedup vs baseline: 1.1832x; 1.1832x over previous
//
#include <hip/hip_runtime.h>

#define NN 20000
#define NE 320000
#define EP (NE + NN)          // 340000 edges incl. self loops
#define NG 8
#define HC 256
#define NODE_IN 18
#define HID 64
#define NEG_SLOPE 0.2f
#define BN_EPS 1e-5f

// ---------------- workspace layout (float offsets) ----------------
// audited non-overlapping (bf16 [NN*64] = 640000 FLOATS -> 320000 floats of storage? no:
// NN*64 ushorts = 1.28M ushorts = 640000 floats of space)
#define OFF_XL    0u                      // bf16 [NN*256]; also rank[NE] during CSR build
#define OFF_XR    5120000u                // fp32 [NN*256] -> 10240000
#define OFF_H1    10240000u               // bf16 [NN*256] -> 12800000
#define OFF_WTL   12800000u               // bf16 [256*256] -> 12832768
#define OFF_WTR   12832768u               // bf16 [256*256] -> 12865536
#define OFF_P     13000000u               // bf16 [NN*64] (640000 fl) -> 13640000
#define OFF_H2B   13700000u               // bf16 [NN*64] (640000 fl) -> 14340000
#define OFF_H0    15360000u               // fp32 [NN*64] -> 16640000
#define OFF_H3    16640000u               // fp32 [NN*64] -> 17920000
#define OFF_ZERO  18000000u               // start of zeroed region
#define OFF_CNT   18000000u               // uint cnt [NN]
#define OFF_PSUM  18020000u               // [8*64]
#define OFF_PMAX  18020512u               // [8*64]
#define OFF_PCNT  18021024u               // [16]
#define ZERO_FLOATS (18021040u - 18000000u)
#define OFF_EACSR 18021040u               // [EP*4] CSR-ordered edge attrs
#define OFF_RP    19381040u               // int [NN+1]
#define OFF_SRC   19421041u               // int [EP] (self-loop = LAST slot of row, sign bit)
#define OFF_BSUM  19761056u               // int [32]

#define SCAN_ELEM 1024
#define SCAN_NB ((NN + SCAN_ELEM - 1) / SCAN_ELEM)   // 20
#define NB32 (NN / 32)                                // 625

// k_pre grid partition
#define PRE_CNT_NB 1250
#define PRE_CAST_NB 512
#define PRE_ENC_NB 1250
// k_post grid partition
#define POST_EH_NB (NE / 256)             // 1250 (thread per edge)
#define POST_POOL_NB ((NN + 255) / 256)   // 79

typedef __attribute__((ext_vector_type(8))) short bf16x8_t;
typedef __attribute__((ext_vector_type(4))) float f32x4_t;

__device__ __forceinline__ ushort f2bf(float f) {   // RNE float->bf16
  unsigned u = __float_as_uint(f);
  unsigned r = (u + 0x7fffu + ((u >> 16) & 1u)) >> 16;
  return (ushort)r;
}
__device__ __forceinline__ float bf2f(ushort b) {
  return __uint_as_float(((unsigned)b) << 16);
}

// ------------------------------------------------------------------
// K_pre: count (atomic rank) || g2 weight casts || encoder — independent.
#define ENC_NPW 4
__global__ __launch_bounds__(256) void k_pre(
    const int* __restrict__ ei, unsigned* __restrict__ cnt, int* __restrict__ rank,
    const float* __restrict__ Wl, const float* __restrict__ Wr,
    ushort* __restrict__ WtL, ushort* __restrict__ WtR,
    const float* __restrict__ x, const float* __restrict__ ew1, const float* __restrict__ eb1,
    const float* __restrict__ ew2, const float* __restrict__ eb2, float* __restrict__ h0) {
  __shared__ float W1[NODE_IN * HID];
  __shared__ float W2[HID * HID];
  __shared__ float B1s[HID];
  __shared__ float B2s[HID];
  __shared__ float hid_s[4][HID];
  const int b = blockIdx.x;
  const int tid = threadIdx.x;
  if (b < PRE_CNT_NB) {
    int e = b * 256 + tid;
    if (e < NE) {
      int d = ei[NE + e];
      rank[e] = (int)atomicAdd(&cnt[d], 1u);
    }
    return;
  }
  if (b < PRE_CNT_NB + PRE_CAST_NB) {
    int bb = b - PRE_CNT_NB;
    const float* W = (bb < 256) ? Wl : Wr;
    ushort* Wt = (bb < 256) ? WtL : WtR;
    int k = bb & 255;
    Wt[tid * 256 + k] = f2bf(W[k * 256 + tid]);
    return;
  }
  // encoder
  const int eb = b - PRE_CNT_NB - PRE_CAST_NB;
  for (int i = tid; i < NODE_IN * HID; i += 256) W1[i] = ew1[i];
  for (int i = tid; i < HID * HID; i += 256) W2[i] = ew2[i];
  if (tid < HID) { B1s[tid] = eb1[tid]; B2s[tid] = eb2[tid]; }
  __syncthreads();
  const int lane = tid & 63;
  const int w = tid >> 6;
  #pragma unroll
  for (int t = 0; t < ENC_NPW; t++) {
    const int n = eb * (4 * ENC_NPW) + w * ENC_NPW + t;
    const float* xp = &x[(size_t)n * NODE_IN];
    float s = B1s[lane];
    #pragma unroll
    for (int i = 0; i < NODE_IN; i++) s += xp[i] * W1[i * HID + lane];
    hid_s[w][lane] = fmaxf(s, 0.f);
    float o = B2s[lane];
    #pragma unroll 8
    for (int k = 0; k < HID; k++) o += hid_s[w][k] * W2[k * HID + lane];
    h0[(size_t)n * HID + lane] = o;
  }
}

// ------------------------------------------------------------------
__global__ __launch_bounds__(256) void k_scan_blk(
    const unsigned* __restrict__ cnt, int* __restrict__ row_ptr, int* __restrict__ bsums) {
  __shared__ int wsum[4];
  const int tid = threadIdx.x, lane = tid & 63, w = tid >> 6;
  const int i0 = blockIdx.x * SCAN_ELEM + tid * 4;
  int v0 = (i0 + 0 < NN) ? ((int)cnt[i0 + 0] + 1) : 0;
  int v1 = (i0 + 1 < NN) ? ((int)cnt[i0 + 1] + 1) : 0;
  int v2 = (i0 + 2 < NN) ? ((int)cnt[i0 + 2] + 1) : 0;
  int v3 = (i0 + 3 < NN) ? ((int)cnt[i0 + 3] + 1) : 0;
  int tsum = v0 + v1 + v2 + v3;
  int incl = tsum;
  #pragma unroll
  for (int off = 1; off < 64; off <<= 1) {
    int t = __shfl_up(incl, off);
    if (lane >= off) incl += t;
  }
  if (lane == 63) wsum[w] = incl;
  __syncthreads();
  int p = incl - tsum;
  #pragma unroll
  for (int k = 0; k < 4; k++) if (k < w) p += wsum[k];
  if (i0 + 0 < NN) row_ptr[i0 + 0] = p;
  if (i0 + 1 < NN) row_ptr[i0 + 1] = p + v0;
  if (i0 + 2 < NN) row_ptr[i0 + 2] = p + v0 + v1;
  if (i0 + 3 < NN) row_ptr[i0 + 3] = p + v0 + v1 + v2;
  if (tid == 0) bsums[blockIdx.x] = wsum[0] + wsum[1] + wsum[2] + wsum[3];
}

__global__ __launch_bounds__(256) void k_scan_add(
    const int* __restrict__ bsums, int* __restrict__ row_ptr) {
  const int b = blockIdx.x, tid = threadIdx.x;
  int off = 0;
  for (int j = 0; j < b; j++) off += bsums[j];
  const int i0 = b * SCAN_ELEM + tid * 4;
  #pragma unroll
  for (int k = 0; k < 4; k++) {
    int i = i0 + k;
    if (i < NN) row_ptr[i] += off;
  }
  if (b == 0 && tid == 0) row_ptr[NN] = EP;
}

__global__ __launch_bounds__(256) void k_csr_scatter(
    const int* __restrict__ ei, const int* __restrict__ rank,
    const int* __restrict__ row_ptr, const float* __restrict__ ea,
    int* __restrict__ srcs, float* __restrict__ ea_csr) {
  int e = blockIdx.x * 256 + threadIdx.x;
  if (e >= NE) return;
  int s = ei[e], d = ei[NE + e];
  int p = row_ptr[d] + rank[e];
  srcs[p] = s;
  *(float4*)&ea_csr[(size_t)p * 4] = *(const float4*)&ea[(size_t)e * 4];
}

// K_loop_row: wave-per-node self-loop mean.
__global__ __launch_bounds__(256) void k_loop_row(
    const int* __restrict__ row_ptr, int* __restrict__ srcs, float* __restrict__ ea_csr) {
  int lane = threadIdx.x & 63, w = threadIdx.x >> 6;
  int i = blockIdx.x * 4 + w;
  int start = row_ptr[i], last = row_ptr[i + 1] - 1;
  float s = 0.f;
  int base = start * 4;
  int nfl = (last - start) * 4;
  for (int f = lane; f < nfl; f += 64) s += ea_csr[base + f];
  s += __shfl_xor(s, 4);
  s += __shfl_xor(s, 8);
  s += __shfl_xor(s, 16);
  s += __shfl_xor(s, 32);
  float c = (float)(last - start);
  if (c < 1.f) c = 1.f;
  if (lane < 4) ea_csr[(size_t)last * 4 + lane] = s / c;
  if (lane == 0) srcs[last] = i | (int)0x80000000;
}

// ------------------------------------------------------------------
// K4: fp32 vector GEMM (layer-1, K=64), DUAL.
__global__ __launch_bounds__(256) void k_gemm256_dual(
    const float* __restrict__ A, const float* __restrict__ Wl_, const float* __restrict__ Wr_,
    ushort* __restrict__ OUTbf, float* __restrict__ OUTf) {
  const bool first = blockIdx.x < NB32;
  const float* __restrict__ W = first ? Wl_ : Wr_;
  const int n0 = (first ? blockIdx.x : blockIdx.x - NB32) * 32;
  __shared__ float Wlds[32 * 256];
  __shared__ float Al[32 * 36];
  const int tid = threadIdx.x;
  const int tx = tid & 63, ty = tid >> 6;
  float acc[8][4];
  #pragma unroll
  for (int m = 0; m < 8; m++)
    #pragma unroll
    for (int c = 0; c < 4; c++) acc[m][c] = 0.f;

  for (int kt = 0; kt < 64; kt += 32) {
    #pragma unroll
    for (int r = 0; r < 8; r++) {
      int i4 = tid + 256 * r;
      int row = i4 >> 6;
      int col4 = (i4 & 63) * 4;
      *(float4*)&Wlds[row * 256 + col4] = *(const float4*)&W[(size_t)(kt + row) * 256 + col4];
    }
    {
      int m = tid >> 3, kk = (tid & 7) * 4;
      float4 av = *(const float4*)&A[(size_t)(n0 + m) * 64 + kt + kk];
      Al[(kk + 0) * 36 + m] = av.x;
      Al[(kk + 1) * 36 + m] = av.y;
      Al[(kk + 2) * 36 + m] = av.z;
      Al[(kk + 3) * 36 + m] = av.w;
    }
    __syncthreads();
    #pragma unroll 8
    for (int k = 0; k < 32; k++) {
      float4 b = *(float4*)&Wlds[k * 256 + tx * 4];
      float4 a0v = *(float4*)&Al[k * 36 + ty * 8];
      float4 a1v = *(float4*)&Al[k * 36 + ty * 8 + 4];
      float am[8] = {a0v.x, a0v.y, a0v.z, a0v.w, a1v.x, a1v.y, a1v.z, a1v.w};
      #pragma unroll
      for (int m = 0; m < 8; m++) {
        acc[m][0] += am[m] * b.x;
        acc[m][1] += am[m] * b.y;
        acc[m][2] += am[m] * b.z;
        acc[m][3] += am[m] * b.w;
      }
    }
    __syncthreads();
  }
  if (first) {
    #pragma unroll
    for (int m = 0; m < 8; m++) {
      ushort4 o = {f2bf(acc[m][0]), f2bf(acc[m][1]), f2bf(acc[m][2]), f2bf(acc[m][3])};
      *(ushort4*)&OUTbf[(size_t)(n0 + ty * 8 + m) * 256 + tx * 4] = o;
    }
  } else {
    #pragma unroll
    for (int m = 0; m < 8; m++) {
      float4 o = {acc[m][0], acc[m][1], acc[m][2], acc[m][3]};
      *(float4*)&OUTf[(size_t)(n0 + ty * 8 + m) * 256 + tx * 4] = o;
    }
  }
}

// ------------------------------------------------------------------
// K4b: MFMA bf16 GEMM (layer-2, K=256), DUAL.
__global__ __launch_bounds__(256) void k_gemm_mfma_dual(
    const ushort* __restrict__ A, const ushort* __restrict__ wtl,
    const ushort* __restrict__ wtr, ushort* __restrict__ OUTbf, float* __restrict__ OUTf) {
  const bool first = blockIdx.x < NB32;
  const ushort* __restrict__ Wt = first ? wtl : wtr;
  const int n0 = (first ? blockIdx.x : blockIdx.x - NB32) * 32;
  __shared__ ushort Asub[32][72];
  __shared__ ushort Wsub[256][72];
  const int tid = threadIdx.x;
  const int lane = tid & 63;
  const int w = tid >> 6;
  const int lr = lane & 15;
  const int lk = (lane >> 4) * 8;

  f32x4_t acc[2][4];
  #pragma unroll
  for (int m = 0; m < 2; m++)
    #pragma unroll
    for (int n = 0; n < 4; n++) acc[m][n] = (f32x4_t){0.f, 0.f, 0.f, 0.f};

  for (int kt = 0; kt < 256; kt += 64) {
    {
      int r = tid >> 3, seg = (tid & 7) * 8;
      *(uint4*)&Asub[r][seg] = *(const uint4*)&A[(size_t)(n0 + r) * 256 + kt + seg];
    }
    #pragma unroll
    for (int rep = 0; rep < 8; rep++) {
      int idx = rep * 256 + tid;
      int r = idx >> 3, seg = (idx & 7) * 8;
      *(uint4*)&Wsub[r][seg] = *(const uint4*)&Wt[(size_t)r * 256 + kt + seg];
    }
    __syncthreads();
    #pragma unroll
    for (int kk = 0; kk < 2; kk++) {
      bf16x8_t af0 = *(bf16x8_t*)&Asub[lr][kk * 32 + lk];
      bf16x8_t af1 = *(bf16x8_t*)&Asub[16 + lr][kk * 32 + lk];
      #pragma unroll
      for (int n = 0; n < 4; n++) {
        bf16x8_t bfr = *(bf16x8_t*)&Wsub[w * 64 + n * 16 + lr][kk * 32 + lk];
        acc[0][n] = __builtin_amdgcn_mfma_f32_16x16x32_bf16(af0, bfr, acc[0][n], 0, 0, 0);
        acc[1][n] = __builtin_amdgcn_mfma_f32_16x16x32_bf16(af1, bfr, acc[1][n], 0, 0, 0);
      }
    }
    __syncthreads();
  }
  const int crow = (lane >> 4) * 4;
  #pragma unroll
  for (int m = 0; m < 2; m++) {
    #pragma unroll
    for (int n = 0; n < 4; n++) {
      int col = w * 64 + n * 16 + lr;
      #pragma unroll
      for (int r = 0; r < 4; r++) {
        int row = n0 + m * 16 + crow + r;
        if (first) OUTbf[(size_t)row * 256 + col] = f2bf(acc[m][n][r]);
        else       OUTf[(size_t)row * 256 + col] = acc[m][n][r];
      }
    }
  }
}

// ------------------------------------------------------------------
// K5: fused GATv2 — 4-edge unroll, QUAD independent streams, direct-exp.
#define GAT_EDGE(A_, U_, DN_, C0_, C1_, C2_, C3_)                                  \
  {                                                                                \
    float xx_ = bf2f((U_).x), xy_ = bf2f((U_).y), xz_ = bf2f((U_).z), xw_ = bf2f((U_).w); \
    float m0_ = xx_ + xrd.x + (A_).x * we0.x + (A_).y * we1.x + (A_).z * we2.x + (A_).w * we3.x; \
    float m1_ = xy_ + xrd.y + (A_).x * we0.y + (A_).y * we1.y + (A_).z * we2.y + (A_).w * we3.y; \
    float m2_ = xz_ + xrd.z + (A_).x * we0.z + (A_).y * we1.z + (A_).z * we2.z + (A_).w * we3.z; \
    float m3_ = xw_ + xrd.w + (A_).x * we0.w + (A_).y * we1.w + (A_).z * we2.w + (A_).w * we3.w; \
    m0_ = fmaxf(m0_, NEG_SLOPE * m0_);                                             \
    m1_ = fmaxf(m1_, NEG_SLOPE * m1_);                                             \
    m2_ = fmaxf(m2_, NEG_SLOPE * m2_);                                             \
    m3_ = fmaxf(m3_, NEG_SLOPE * m3_);                                             \
    float lg_ = m0_ * attv.x + m1_ * attv.y + m2_ * attv.z + m3_ * attv.w;         \
    lg_ += __shfl_xor(lg_, 1);                                                     \
    lg_ += __shfl_xor(lg_, 2);                                                     \
    lg_ += __shfl_xor(lg_, 4);                                                     \
    lg_ += __shfl_xor(lg_, 8);                                                     \
    float p_ = __expf(lg_);                                                        \
    DN_ += p_;                                                                     \
    C0_ = fmaf(p_, xx_, C0_);                                                      \
    C1_ = fmaf(p_, xy_, C1_);                                                      \
    C2_ = fmaf(p_, xz_, C2_);                                                      \
    C3_ = fmaf(p_, xw_, C3_);                                                      \
  }

template <int CONCAT>
__global__ __launch_bounds__(256) void k_gat_fused(
    const ushort* __restrict__ xl, const float* __restrict__ xr,
    const float* __restrict__ we, const float* __restrict__ att,
    const int* __restrict__ srcs, const float* __restrict__ ea_csr,
    const int* __restrict__ row_ptr,
    const float* __restrict__ bias, const float* __restrict__ bng,
    const float* __restrict__ bnb, void* __restrict__ outp,
    ushort* __restrict__ outbf2) {
  const int lane = threadIdx.x & 63;
  const int w = threadIdx.x >> 6;
  const int i = blockIdx.x * 4 + w;
  const int c0 = lane * 4;

  const float4 attv = *(const float4*)&att[c0];
  const float4 we0 = *(const float4*)&we[0 * HC + c0];
  const float4 we1 = *(const float4*)&we[1 * HC + c0];
  const float4 we2 = *(const float4*)&we[2 * HC + c0];
  const float4 we3 = *(const float4*)&we[3 * HC + c0];
  const float4 xrd = *(const float4*)&xr[(size_t)i * HC + c0];

  const int start = row_ptr[i];
  const int deg = row_ptr[i + 1] - start;

  float dnA = 0.f, aA0 = 0.f, aA1 = 0.f, aA2 = 0.f, aA3 = 0.f;
  float dnB = 0.f, aB0 = 0.f, aB1 = 0.f, aB2 = 0.f, aB3 = 0.f;
  float dnC = 0.f, aC0 = 0.f, aC1 = 0.f, aC2 = 0.f, aC3 = 0.f;
  float dnD = 0.f, aD0 = 0.f, aD1 = 0.f, aD2 = 0.f, aD3 = 0.f;

  for (int base = 0; base < deg; base += 64) {
    int rem = deg - base;
    if (rem > 64) rem = 64;
    int sv = 0;
    if (lane < rem) sv = srcs[start + base + lane] & 0x7fffffff;
    const float4* eaB = (const float4*)&ea_csr[(size_t)(start + base) * 4];
    int jj = 0;
    for (; jj + 4 <= rem; jj += 4) {
      int s0 = __shfl(sv, jj);
      int s1 = __shfl(sv, jj + 1);
      int s2 = __shfl(sv, jj + 2);
      int s3 = __shfl(sv, jj + 3);
      float4 a0 = eaB[jj];
      float4 a1 = eaB[jj + 1];
      float4 a2 = eaB[jj + 2];
      float4 a3 = eaB[jj + 3];
      ushort4 u0 = *(const ushort4*)&xl[(size_t)s0 * HC + c0];
      ushort4 u1 = *(const ushort4*)&xl[(size_t)s1 * HC + c0];
      ushort4 u2 = *(const ushort4*)&xl[(size_t)s2 * HC + c0];
      ushort4 u3 = *(const ushort4*)&xl[(size_t)s3 * HC + c0];
      GAT_EDGE(a0, u0, dnA, aA0, aA1, aA2, aA3);
      GAT_EDGE(a1, u1, dnB, aB0, aB1, aB2, aB3);
      GAT_EDGE(a2, u2, dnC, aC0, aC1, aC2, aC3);
      GAT_EDGE(a3, u3, dnD, aD0, aD1, aD2, aD3);
    }
    for (; jj < rem; ++jj) {   // tail edges -> stream A
      int s0 = __shfl(sv, jj);
      float4 a0 = eaB[jj];
      ushort4 u0 = *(const ushort4*)&xl[(size_t)s0 * HC + c0];
      GAT_EDGE(a0, u0, dnA, aA0, aA1, aA2, aA3);
    }
  }

  float rinv = 1.f / ((dnA + dnB) + (dnC + dnD));
  float acc0 = ((aA0 + aB0) + (aC0 + aD0)) * rinv;
  float acc1 = ((aA1 + aB1) + (aC1 + aD1)) * rinv;
  float acc2 = ((aA2 + aB2) + (aC2 + aD2)) * rinv;
  float acc3 = ((aA3 + aB3) + (aC3 + aD3)) * rinv;

  const float inv_sqrt = rsqrtf(1.f + BN_EPS);
  if (CONCAT) {
    float4 bi = *(const float4*)&bias[c0];
    float4 g = *(const float4*)&bng[c0];
    float4 bb = *(const float4*)&bnb[c0];
    float v0 = (acc0 + bi.x) * (g.x * inv_sqrt) + bb.x;
    float v1 = (acc1 + bi.y) * (g.y * inv_sqrt) + bb.y;
    float v2 = (acc2 + bi.z) * (g.z * inv_sqrt) + bb.z;
    float v3 = (acc3 + bi.w) * (g.w * inv_sqrt) + bb.w;
    v0 = (v0 > 0.f) ? v0 : (__expf(v0) - 1.f);
    v1 = (v1 > 0.f) ? v1 : (__expf(v1) - 1.f);
    v2 = (v2 > 0.f) ? v2 : (__expf(v2) - 1.f);
    v3 = (v3 > 0.f) ? v3 : (__expf(v3) - 1.f);
    ushort* op = (ushort*)outp;                      // h1 stored bf16 for MFMA
    ushort4 o = {f2bf(v0), f2bf(v1), f2bf(v2), f2bf(v3)};
    *(ushort4*)&op[(size_t)i * HC + c0] = o;
  } else {
    acc0 += __shfl_xor(acc0, 16); acc0 += __shfl_xor(acc0, 32);
    acc1 += __shfl_xor(acc1, 16); acc1 += __shfl_xor(acc1, 32);
    acc2 += __shfl_xor(acc2, 16); acc2 += __shfl_xor(acc2, 32);
    acc3 += __shfl_xor(acc3, 16); acc3 += __shfl_xor(acc3, 32);
    if (lane < 16) {
      int cc = lane * 4;
      float4 bi = *(const float4*)&bias[cc];
      float4 g = *(const float4*)&bng[cc];
      float4 bb = *(const float4*)&bnb[cc];
      float v0 = (0.25f * acc0 + bi.x) * (g.x * inv_sqrt) + bb.x;
      float v1 = (0.25f * acc1 + bi.y) * (g.y * inv_sqrt) + bb.y;
      float v2 = (0.25f * acc2 + bi.z) * (g.z * inv_sqrt) + bb.z;
      float v3 = (0.25f * acc3 + bi.w) * (g.w * inv_sqrt) + bb.w;
      v0 = (v0 > 0.f) ? v0 : (__expf(v0) - 1.f);
      v1 = (v1 > 0.f) ? v1 : (__expf(v1) - 1.f);
      v2 = (v2 > 0.f) ? v2 : (__expf(v2) - 1.f);
      v3 = (v3 > 0.f) ? v3 : (__expf(v3) - 1.f);
      float* op = (float*)outp;
      float4 o = {v0, v1, v2, v3};
      *(float4*)&op[(size_t)i * 64 + cc] = o;
      ushort4 ob = {f2bf(v0), f2bf(v1), f2bf(v2), f2bf(v3)};
      *(ushort4*)&outbf2[(size_t)i * 64 + cc] = ob;  // h2 bf16 mirror for SAGE
    }
  }
}

// ------------------------------------------------------------------
// K8: fused SAGE (bf16 neighbor gathers) + edge-head node projections (bf16).
__global__ __launch_bounds__(256) void k_sage(
    const float* __restrict__ h2, const ushort* __restrict__ h2b,
    const int* __restrict__ row_ptr,
    const int* __restrict__ srcs, const unsigned* __restrict__ cnt,
    const float* __restrict__ wl, const float* __restrict__ bl,
    const float* __restrict__ wr, const float* __restrict__ bng,
    const float* __restrict__ bnb, const float* __restrict__ w1eh,
    float* __restrict__ h3, ushort* __restrict__ P) {
  __shared__ float Wc[64][64];      // 16 KB: [k][j] = W1a/W1b column mix
  __shared__ float agg_s[4][64];
  __shared__ float h2_s[4][64];
  int tid = threadIdx.x;
  for (int idx = tid; idx < 4096; idx += 256) {
    int k = idx >> 6, j = idx & 63;
    Wc[k][j] = (j < 32) ? w1eh[k * 32 + j] : w1eh[(64 + k) * 32 + (j - 32)];
  }
  int lane = tid & 63;
  int w = tid >> 6;
  int i = blockIdx.x * 4 + w;
  int start = row_ptr[i];
  int nreal = row_ptr[i + 1] - 1 - start;
  float a0 = 0.f, a1 = 0.f, a2 = 0.f, a3 = 0.f;
  for (int base = 0; base < nreal; base += 64) {
    int rem = nreal - base;
    if (rem > 64) rem = 64;
    int sv = 0;
    if (lane < rem) sv = srcs[start + base + lane];
    int jj = 0;
    for (; jj + 4 <= rem; jj += 4) {
      int s0 = __shfl(sv, jj);
      int s1 = __shfl(sv, jj + 1);
      int s2 = __shfl(sv, jj + 2);
      int s3 = __shfl(sv, jj + 3);
      a0 += bf2f(h2b[(size_t)s0 * 64 + lane]);
      a1 += bf2f(h2b[(size_t)s1 * 64 + lane]);
      a2 += bf2f(h2b[(size_t)s2 * 64 + lane]);
      a3 += bf2f(h2b[(size_t)s3 * 64 + lane]);
    }
    for (; jj < rem; ++jj) {
      int s0 = __shfl(sv, jj);
      a0 += bf2f(h2b[(size_t)s0 * 64 + lane]);
    }
  }
  float a = (a0 + a1) + (a2 + a3);
  float c = (float)cnt[i];
  if (c < 1.f) c = 1.f;
  agg_s[w][lane] = a / c;
  h2_s[w][lane] = h2[(size_t)i * 64 + lane];
  __syncthreads();                  // covers Wc staging + agg/h2 writes
  float s = bl[lane];
  #pragma unroll 4
  for (int k = 0; k < 64; k++)
    s += agg_s[w][k] * wl[k * 64 + lane] + h2_s[w][k] * wr[k * 64 + lane];
  s = s * (bng[lane] * rsqrtf(1.f + BN_EPS)) + bnb[lane];
  s = fmaxf(s, 0.f);
  h3[(size_t)i * 64 + lane] = s;
  agg_s[w][lane] = s;               // wave-local reuse: h3 row broadcast
  float p = 0.f;
  #pragma unroll 4
  for (int k = 0; k < 64; k++) p += agg_s[w][k] * Wc[k][lane];
  P[(size_t)i * 64 + lane] = f2bf(p);
}

// ------------------------------------------------------------------
// K_post: edge head (thread/edge, gathers bf16 P) || pooling.
__global__ __launch_bounds__(256) void k_post(
    const ushort* __restrict__ P, const int* __restrict__ ei,
    const float* __restrict__ ea, const float* __restrict__ w1eh,
    const float* __restrict__ b1, const float* __restrict__ w2,
    const float* __restrict__ b2, float* __restrict__ out,
    const float* __restrict__ h3, const int* __restrict__ batch,
    float* __restrict__ psum, float* __restrict__ pmax, float* __restrict__ pcnt) {
  const int tid = threadIdx.x;
  if (blockIdx.x >= POST_EH_NB) {
    // ---- pooling branch ----
    int pb = blockIdx.x - POST_EH_NB;
    int j = tid & 63, grp = tid >> 6;
    int nbase = pb * 256 + grp * 64;
    float s = 0.f, m = 0.f, cn = 0.f;
    int cur = -1;
    for (int t = 0; t < 64; t++) {
      int n = nbase + t;
      if (n >= NN) break;
      int g = batch[n];
      if (g != cur) {
        if (cur >= 0) {
          atomicAdd(&psum[cur * 64 + j], s);
          atomicMax((int*)&pmax[cur * 64 + j], __float_as_int(m));
          if (j == 0) atomicAdd(&pcnt[cur], cn);
        }
        cur = g; s = 0.f; m = 0.f; cn = 0.f;
      }
      float v = h3[(size_t)n * 64 + j];
      s += v; m = fmaxf(m, v); cn += 1.f;
    }
    if (cur >= 0) {
      atomicAdd(&psum[cur * 64 + j], s);
      atomicMax((int*)&pmax[cur * 64 + j], __float_as_int(m));
      if (j == 0) atomicAdd(&pcnt[cur], cn);
    }
    return;
  }
  // ---- edge head branch: one thread per edge ----
  const int e = blockIdx.x * 256 + tid;
  const int sn = ei[e], dn = ei[NE + e];
  const ushort* Ps = &P[(size_t)sn * 64];        // src projection (cols 0..31)
  const ushort* Pd = &P[(size_t)dn * 64 + 32];   // dst projection (cols 32..63)
  float acc[32];
  #pragma unroll
  for (int f = 0; f < 4; f++) {
    ushort u1[8], u2[8];
    *(uint4*)u1 = *(const uint4*)&Ps[f * 8];
    *(uint4*)u2 = *(const uint4*)&Pd[f * 8];
    #pragma unroll
    for (int j = 0; j < 8; j++) acc[f * 8 + j] = bf2f(u1[j]) + bf2f(u2[j]);
  }
  float4 av = *(const float4*)&ea[(size_t)e * 4];
  const float* w1c = &w1eh[128 * 32];           // rows 128..131 (edge_attr part)
  float z = 0.f;
  #pragma unroll
  for (int j = 0; j < 32; j++) {
    float v = acc[j] + b1[j]
            + av.x * w1c[j] + av.y * w1c[32 + j]
            + av.z * w1c[64 + j] + av.w * w1c[96 + j];
    z += fmaxf(v, 0.f) * w2[j];
  }
  out[e] = 1.f / (1.f + __expf(-(z + b2[0])));
}

// ------------------------------------------------------------------
__global__ void k_graph_head(
    const float* __restrict__ psum, const float* __restrict__ pmax,
    const float* __restrict__ pcnt,
    const float* __restrict__ w1, const float* __restrict__ b1,
    const float* __restrict__ w2, const float* __restrict__ b2,
    const float* __restrict__ w3, const float* __restrict__ b3,
    float* __restrict__ out) {
  __shared__ float hp[128];
  __shared__ float z1[64];
  __shared__ float z2[32];
  int g = blockIdx.x, j = threadIdx.x;
  float c = pcnt[g];
  if (c < 1.f) c = 1.f;
  hp[j] = psum[g * 64 + j] / c;
  hp[64 + j] = pmax[g * 64 + j];
  __syncthreads();
  float s = b1[j];
  #pragma unroll 8
  for (int k = 0; k < 128; k++) s += hp[k] * w1[k * 64 + j];
  z1[j] = fmaxf(s, 0.f);
  __syncthreads();
  if (j < 32) {
    float s2 = b2[j];
    #pragma unroll 8
    for (int k = 0; k < 64; k++) s2 += z1[k] * w2[k * 32 + j];
    z2[j] = fmaxf(s2, 0.f);
  }
  __syncthreads();
  if (j == 0) {
    float s3 = b3[0];
    #pragma unroll
    for (int k = 0; k < 32; k++) s3 += z2[k] * w3[k];
    out[g] = 1.f / (1.f + expf(-s3));
  }
}

// ------------------------------------------------------------------
extern "C" void kernel_launch(void* const* d_in, const int* in_sizes, int n_in,
                              void* d_out, int out_size, void* d_ws, size_t ws_size,
                              hipStream_t stream) {
  const float* x         = (const float*)d_in[0];
  const float* edge_attr = (const float*)d_in[1];
  const float* enc_w1 = (const float*)d_in[2];
  const float* enc_b1 = (const float*)d_in[3];
  const float* enc_w2 = (const float*)d_in[4];
  const float* enc_b2 = (const float*)d_in[5];
  const float* g1_wl = (const float*)d_in[6];
  const float* g1_wr = (const float*)d_in[7];
  const float* g1_we = (const float*)d_in[8];
  const float* g1_att = (const float*)d_in[9];
  const float* g1_b = (const float*)d_in[10];
  const float* bn1_g = (const float*)d_in[11];
  const float* bn1_b = (const float*)d_in[12];
  const float* g2_wl = (const float*)d_in[13];
  const float* g2_wr = (const float*)d_in[14];
  const float* g2_we = (const float*)d_in[15];
  const float* g2_att = (const float*)d_in[16];
  const float* g2_b = (const float*)d_in[17];
  const float* bn2_g = (const float*)d_in[18];
  const float* bn2_b = (const float*)d_in[19];
  const float* sage_wl = (const float*)d_in[20];
  const float* sage_bl = (const float*)d_in[21];
  const float* sage_wr = (const float*)d_in[22];
  const float* bn3_g = (const float*)d_in[23];
  const float* bn3_b = (const float*)d_in[24];
  const float* gh_w1 = (const float*)d_in[25];
  const float* gh_b1 = (const float*)d_in[26];
  const float* gh_w2 = (const float*)d_in[27];
  const float* gh_b2 = (const float*)d_in[28];
  const float* gh_w3 = (const float*)d_in[29];
  const float* gh_b3 = (const float*)d_in[30];
  const float* eh_w1 = (const float*)d_in[31];
  const float* eh_b1 = (const float*)d_in[32];
  const float* eh_w2 = (const float*)d_in[33];
  const float* eh_b2 = (const float*)d_in[34];
  const int* ei    = (const int*)d_in[35];
  const int* batch = (const int*)d_in[36];
  float* out = (float*)d_out;

  float* ws = (float*)d_ws;
  ushort* xlbf = (ushort*)(ws + OFF_XL);
  float* xr = ws + OFF_XR;
  ushort* h1bf = (ushort*)(ws + OFF_H1);
  ushort* wtl = (ushort*)(ws + OFF_WTL);
  ushort* wtr = (ushort*)(ws + OFF_WTR);
  ushort* Pproj = (ushort*)(ws + OFF_P);
  ushort* h2b = (ushort*)(ws + OFF_H2B);
  float* h0 = ws + OFF_H0;   // later h2
  float* h3 = ws + OFF_H3;
  unsigned* cnt = (unsigned*)(ws + OFF_CNT);
  float* psum = ws + OFF_PSUM;
  float* pmax = ws + OFF_PMAX;
  float* pcnt = ws + OFF_PCNT;
  float* ea_csr = ws + OFF_EACSR;
  int* row_ptr = (int*)(ws + OFF_RP);
  int* srcs = (int*)(ws + OFF_SRC);
  int* bsums = (int*)(ws + OFF_BSUM);
  int* rank = (int*)(ws + OFF_XL);   // transient

  hipMemsetAsync(ws + OFF_ZERO, 0, ZERO_FLOATS * sizeof(float), stream);

  k_pre<<<PRE_CNT_NB + PRE_CAST_NB + PRE_ENC_NB, 256, 0, stream>>>(
      ei, cnt, rank, g2_wl, g2_wr, wtl, wtr,
      x, enc_w1, enc_b1, enc_w2, enc_b2, h0);
  k_scan_blk<<<SCAN_NB, 256, 0, stream>>>(cnt, row_ptr, bsums);
  k_scan_add<<<SCAN_NB, 256, 0, stream>>>(bsums, row_ptr);
  k_csr_scatter<<<NE / 256, 256, 0, stream>>>(ei, rank, row_ptr, edge_attr, srcs, ea_csr);
  k_loop_row<<<NN / 4, 256, 0, stream>>>(row_ptr, srcs, ea_csr);

  // ---- GAT layer 1 (fp32 vector GEMMs, K=64, dual launch) ----
  k_gemm256_dual<<<2 * NB32, 256, 0, stream>>>(h0, g1_wl, g1_wr, xlbf, xr);
  k_gat_fused<1><<<NN / 4, 256, 0, stream>>>(xlbf, xr, g1_we, g1_att, srcs, ea_csr,
                                             row_ptr, g1_b, bn1_g, bn1_b, (void*)h1bf, nullptr);

  // ---- GAT layer 2 (MFMA bf16 GEMMs, K=256, dual launch) ----
  k_gemm_mfma_dual<<<2 * NB32, 256, 0, stream>>>(h1bf, wtl, wtr, xlbf, xr);
  k_gat_fused<0><<<NN / 4, 256, 0, stream>>>(xlbf, xr, g2_we, g2_att, srcs, ea_csr,
                                             row_ptr, g2_b, bn2_g, bn2_b, (void*)h0, h2b);

  // ---- SAGE (+ edge-head projections) ----
  k_sage<<<NN / 4, 256, 0, stream>>>(h0, h2b, row_ptr, srcs, cnt, sage_wl, sage_bl, sage_wr,
                                     bn3_g, bn3_b, eh_w1, h3, Pproj);

  // ---- edge head || pooling, then graph head ----
  k_post<<<POST_EH_NB + POST_POOL_NB, 256, 0, stream>>>(
      Pproj, ei, edge_attr, eh_w1, eh_b1, eh_w2, eh_b2, out + NG,
      h3, batch, psum, pmax, pcnt);
  k_graph_head<<<NG, 64, 0, stream>>>(psum, pmax, pcnt, gh_w1, gh_b1, gh_w2, gh_b2, gh_w3, gh_b3, out);
}